// Round 1
// baseline (172.176 us; speedup 1.0000x reference)
//
#include <hip/hip_runtime.h>

// Predictive-coding graph message passing, MI355X — round 11.
// R10 binned accum was instruction-bound: ~16 instr/record (LDS RMW replica
// accumulation) + per-block scan/compact/tree-sum forced by the (row x 8-node)
// bin structure. R11 = exact counting-sort to CSR (hist -> scan -> atomic
// scatter), then per-node VGPR accumulation: half-wave owns one node's
// contiguous records, ~6 instr/record, no LDS RMW, no scan, no compaction.
// Weights kept f32 (absmax ~1e-6 vs bf16's 0.0156). Bins 21MB -> CSR 8MB.

static constexpr int kB = 32, kLogB = 5;
static constexpr int kN = 4096;          // nodes per graph (fixed problem size)
static constexpr int kHB = 128;          // histogram blocks
static constexpr int kSB = 256;          // scatter blocks

// ---- K1: fused transpose/tanh + per-direction histograms. ---------------
__global__ void __launch_bounds__(1024) k_prep(
    const float* __restrict__ x, const int* __restrict__ esrc,
    const int* __restrict__ edst,
    float* __restrict__ x_t, float* __restrict__ fx_t,
    unsigned* __restrict__ g_cntA, unsigned* __restrict__ g_cntB,
    int N, int E) {
  __shared__ unsigned hA[kN], hB[kN];    // 32 KB
  __shared__ float tile[32][65];
  int tid = threadIdx.x, blk = blockIdx.x;

  if (blk < kHB) {
    for (int t = tid; t < kN; t += 1024) { hA[t] = 0u; hB[t] = 0u; }
    __syncthreads();
    int chunk = (E + kHB - 1) / kHB;
    int e0 = blk * chunk, e1 = min(e0 + chunk, E);
    for (int e = e0 + tid; e < e1; e += 1024) {
      atomicAdd(&hA[edst[e]], 1u);       // LDS atomics: native, low contention
      atomicAdd(&hB[esrc[e]], 1u);
    }
    __syncthreads();
    for (int t = tid; t < kN; t += 1024) {
      unsigned a = hA[t], b = hB[t];
      if (a) atomicAdd(&g_cntA[t], a);   // 4096 addrs x kHB adds: parallel
      if (b) atomicAdd(&g_cntB[t], b);
    }
  } else {
    // Transpose/tanh: blocks kHB..kHB+N/64-1 (disjoint LDS arrays).
    int n0 = (blk - kHB) * 64;
    for (int k = tid; k < 32 * 64; k += 1024) {   // coalesced 256B rows
      int b = k >> 6, n = k & 63;
      tile[b][n] = x[b * N + n0 + n];
    }
    __syncthreads();
    for (int k = tid; k < 64 * 32; k += 1024) {   // coalesced t-layout
      int n = k >> 5, b = k & 31;
      float xv = tile[b][n];
      int j = (n0 + n) * kB + b;
      x_t[j] = xv;
      fx_t[j] = tanhf(xv);
    }
  }
}

// ---- K2: exclusive scan of both histograms (block 0 = A, block 1 = B). --
__global__ void __launch_bounds__(1024) k_scan(
    const unsigned* __restrict__ g_cntA, const unsigned* __restrict__ g_cntB,
    unsigned* __restrict__ g_offA, unsigned* __restrict__ g_offB) {
  __shared__ unsigned ssum[1024];
  const unsigned* cnt = blockIdx.x ? g_cntB : g_cntA;
  unsigned* off = blockIdx.x ? g_offB : g_offA;
  int tid = threadIdx.x;
  uint4 c = reinterpret_cast<const uint4*>(cnt)[tid];   // 4 counts/thread
  unsigned s = c.x + c.y + c.z + c.w;
  ssum[tid] = s;
  __syncthreads();
  for (int o = 1; o < 1024; o <<= 1) {                  // Hillis-Steele
    unsigned v = 0;
    if (tid >= o) v = ssum[tid - o];
    __syncthreads();
    if (tid >= o) ssum[tid] += v;
    __syncthreads();
  }
  unsigned base = ssum[tid] - s;                        // exclusive base
  uint4 o4;
  o4.x = base;
  o4.y = base + c.x;
  o4.z = base + c.x + c.y;
  o4.w = base + c.x + c.y + c.z;
  reinterpret_cast<uint4*>(off)[tid] = o4;
}

// ---- K3: scatter edges into dst-sorted (csrA) and src-sorted (csrB) CSR.
// Slot allocation via global atomics: 128 increments/address mean, spread
// over 4096 addresses per direction. Post-kernel, g_off* holds the
// INCLUSIVE scan (start[n] + cnt[n]) — consumed as segment bounds by k_pass.
__global__ void __launch_bounds__(1024) k_scatter(
    const float* __restrict__ w, const int* __restrict__ esrc,
    const int* __restrict__ edst,
    unsigned* __restrict__ g_offA, unsigned* __restrict__ g_offB,
    uint2* __restrict__ csrA, uint2* __restrict__ csrB, int E) {
  int tid = blockIdx.x * 1024 + threadIdx.x;
  int stride = gridDim.x * 1024;
  for (int e = tid; e < E; e += stride) {
    int s = esrc[e], d = edst[e];
    unsigned wbits = __float_as_uint(w[e]);             // full f32 weight
    unsigned a = atomicAdd(&g_offA[d], 1u);
    csrA[a] = make_uint2((unsigned)s, wbits);
    unsigned bsl = atomicAdd(&g_offB[s], 1u);
    csrB[bsl] = make_uint2((unsigned)d, wbits);
  }
}

// ---- K4/K5: per-node VGPR accumulation over contiguous CSR records. -----
// 256 thr = 8 half-waves = 2 nodes x 4 edge-parts; both half-waves of a
// wave share one node -> near-zero divergence. Records uniform per
// half-wave (1 txn); value gather = 128B/record from L2-resident table.
__global__ void __launch_bounds__(256) k_pass(
    const uint2* __restrict__ csr, const unsigned* __restrict__ off,
    const float* __restrict__ vals, const float* __restrict__ x_t,
    const float* __restrict__ fx_t, float* __restrict__ eps_t,
    float* __restrict__ out, int N, int mode) {
  __shared__ float red[256];
  int tid = threadIdx.x;
  int b = tid & 31, hw = tid >> 5;       // batch lane, half-wave slot
  int nl = hw >> 2, part = hw & 3;       // node-in-block, edge part
  int n = blockIdx.x * 2 + nl;
  int lo = n ? (int)off[n - 1] : 0;      // inclusive-scan bounds
  int T = (int)off[n];

  float acc = 0.0f;
  int i = lo + part;
  uint2 z = make_uint2(0u, 0u);
  // 3-deep record / 2-deep value pipeline (proven R8 pattern).
  uint2 r0 = (i < T) ? csr[i] : z;
  uint2 r1 = (i + 4 < T) ? csr[i + 4] : z;
  uint2 r2 = (i + 8 < T) ? csr[i + 8] : z;
  float v0 = (i < T) ? vals[(r0.x << kLogB) + b] : 0.0f;
  float v1 = (i + 4 < T) ? vals[(r1.x << kLogB) + b] : 0.0f;
  while (i < T) {
    uint2 r3 = (i + 12 < T) ? csr[i + 12] : z;
    float v2 = (i + 8 < T) ? vals[(r2.x << kLogB) + b] : 0.0f;
    acc = fmaf(__uint_as_float(r0.y), v0, acc);
    r0 = r1; r1 = r2; r2 = r3;
    v0 = v1; v1 = v2;
    i += 4;
  }
  red[tid] = acc;
  __syncthreads();

  if (part == 0) {                       // hw 0 / hw 4: combine 4 parts
    float s = red[tid] + red[tid + 32] + red[tid + 64] + red[tid + 96];
    int j = n * kB + b;
    if (mode == 0) {
      out[b * N + n] = s;                // mu (batch-major)
      eps_t[j] = x_t[j] - s;
    } else {
      float fx = fx_t[j];
      out[b * N + n] = fmaf(1.0f - fx * fx, s, -eps_t[j]);  // dx
    }
  }
}

extern "C" void kernel_launch(void* const* d_in, const int* in_sizes, int n_in,
                              void* d_out, int out_size, void* d_ws, size_t ws_size,
                              hipStream_t stream) {
  const float* x    = (const float*)d_in[0];
  const float* w    = (const float*)d_in[1];
  const int*   esrc = (const int*)d_in[2];
  const int*   edst = (const int*)d_in[3];

  int BN = in_sizes[0];                  // 131072
  int E  = in_sizes[1];                  // 524288
  int N  = BN / kB;                      // 4096

  float* ws    = (float*)d_ws;
  float* x_t   = ws;                     // [BN]
  float* fx_t  = ws + (size_t)BN;        // [BN]
  float* eps_t = ws + 2 * (size_t)BN;    // [BN]
  unsigned* g_cntA = (unsigned*)(ws + 3 * (size_t)BN);  // [N]
  unsigned* g_cntB = g_cntA + N;                        // [N]
  unsigned* g_offA = g_cntB + N;                        // [N]
  unsigned* g_offB = g_offA + N;                        // [N]
  uint2* csrA = (uint2*)(g_offB + N);                   // [E] 4 MB (8B-aligned)
  uint2* csrB = csrA + (size_t)E;                       // [E] 4 MB

  float* out_mu = (float*)d_out;
  float* out_dx = (float*)d_out + BN;

  // Zero histograms (workspace is poisoned each iteration).
  hipMemsetAsync(g_cntA, 0, (size_t)2 * N * sizeof(unsigned), stream);

  k_prep<<<kHB + (N >> 6), 1024, 0, stream>>>(x, esrc, edst, x_t, fx_t,
                                              g_cntA, g_cntB, N, E);
  k_scan<<<2, 1024, 0, stream>>>(g_cntA, g_cntB, g_offA, g_offB);
  k_scatter<<<kSB, 1024, 0, stream>>>(w, esrc, edst, g_offA, g_offB,
                                      csrA, csrB, E);
  // Pass 1: mu[n] = sum_{e: dst=n} w_e * fx[src_e]; eps = x - mu.
  k_pass<<<N / 2, 256, 0, stream>>>(csrA, g_offA, fx_t, x_t, fx_t,
                                    eps_t, out_mu, N, 0);
  // Pass 2: dx[n] = -eps[n] + f'(x_n) * sum_{e: src=n} w_e * eps[dst_e].
  k_pass<<<N / 2, 256, 0, stream>>>(csrB, g_offB, eps_t, x_t, fx_t,
                                    eps_t, out_dx, N, 1);
}

// Round 2
// 129.360 us; speedup vs baseline: 1.3310x; 1.3310x over previous
//
#include <hip/hip_runtime.h>

// Predictive-coding graph message passing, MI355X — round 12.
// R11's global atomic scatter built a perfect CSR but paid 60us: 1M random
// 8B writes -> 64B-line amplification (58MB HBM writes at 1TB/s), and
// non-coherent per-XCD L2s can't merge partial lines. R12 keeps the per-node
// VGPR accumulation consumer but builds the sorted form hierarchically:
//   k_bucket: LDS counting-sort of 4096-edge chunks into 256 coarse buckets
//             (16 nodes), ONE global atomicAdd per (block,bucket) reserves a
//             contiguous run -> all global writes are >=128B runs from LDS.
//   k_pass:   block = bucket; finish sort in LDS (16 bins), then half-wave
//             per (node,part) VGPR accumulation (R11 consumer, unchanged).
// Deletes k_scan + global CSR round trip. 5 dispatches -> 4 (+2KB memset).

static constexpr int kB = 32, kLogB = 5;
static constexpr int kBkt = 256;         // coarse buckets (16 nodes each)
static constexpr int kNPB = 16;          // nodes per bucket
static constexpr int kCap = 2560;        // records per bucket: mean 2048, +11sigma
static constexpr int kChunk = 4096;      // edges per bucketing block

// ---- K1: fused transpose/tanh + dual-direction LDS bucket sort. ---------
__global__ void __launch_bounds__(1024) k_bucket(
    const float* __restrict__ x, const float* __restrict__ w,
    const int* __restrict__ esrc, const int* __restrict__ edst,
    float* __restrict__ x_t, float* __restrict__ fx_t,
    unsigned* __restrict__ gcntA, unsigned* __restrict__ gcntB,
    uint2* __restrict__ bucketA, uint2* __restrict__ bucketB,
    int N, int E, int nBB) {
  __shared__ unsigned cntL[kBkt];        // per-bucket chunk count
  __shared__ unsigned baseL[kBkt];       // local exclusive scan
  __shared__ unsigned gbase[kBkt];       // reserved global run base
  __shared__ unsigned cnt2[kBkt];        // scatter cursors
  __shared__ uint2 cmp[kChunk];          // 32 KB compacted records
  __shared__ unsigned char bkt[kChunk];  // bucket id per slot
  __shared__ float tile[32][65];
  int tid = threadIdx.x, blk = blockIdx.x;

  if (blk < nBB) {
    int e0 = blk * kChunk;
    int len = min(kChunk, E - e0);
    for (int dir = 0; dir < 2; ++dir) {
      const int* keyArr = dir ? esrc : edst;   // sort key: dst (A) / src (B)
      const int* othArr = dir ? edst : esrc;
      unsigned* gcnt = dir ? gcntB : gcntA;
      uint2* out = dir ? bucketB : bucketA;

      for (int t = tid; t < kBkt; t += 1024) { cntL[t] = 0u; cnt2[t] = 0u; }
      __syncthreads();
#pragma unroll
      for (int k = 0; k < kChunk / 1024; k++) {       // histogram
        int i = k * 1024 + tid;
        if (i < len) atomicAdd(&cntL[((unsigned)keyArr[e0 + i]) >> 4], 1u);
      }
      __syncthreads();
      if (tid < kBkt) baseL[tid] = cntL[tid];
      __syncthreads();
      for (int o = 1; o < kBkt; o <<= 1) {            // Hillis-Steele scan
        unsigned v = 0;
        if (tid < kBkt && tid >= o) v = baseL[tid - o];
        __syncthreads();
        if (tid < kBkt && tid >= o) baseL[tid] += v;
        __syncthreads();
      }
      if (tid < kBkt) {
        unsigned c = cntL[tid];
        gbase[tid] = c ? atomicAdd(&gcnt[tid], c) : 0u;   // ONE atomic/run
        baseL[tid] -= c;                                  // exclusive base
      }
      __syncthreads();
#pragma unroll
      for (int k = 0; k < kChunk / 1024; k++) {       // LDS scatter (sort)
        int i = k * 1024 + tid;
        if (i < len) {
          unsigned key = (unsigned)keyArr[e0 + i];
          unsigned oth = (unsigned)othArr[e0 + i];
          unsigned bb = key >> 4;
          unsigned slot = baseL[bb] + atomicAdd(&cnt2[bb], 1u);
          cmp[slot] = make_uint2((oth << 4) | (key & 15u),
                                 __float_as_uint(w[e0 + i]));
          bkt[slot] = (unsigned char)bb;
        }
      }
      __syncthreads();
#pragma unroll
      for (int k = 0; k < kChunk / 1024; k++) {       // coalesced run copy-out
        int s = k * 1024 + tid;
        if (s < len) {
          unsigned bb = bkt[s];
          unsigned pos = gbase[bb] + ((unsigned)s - baseL[bb]);
          if (pos < kCap) out[(size_t)bb * kCap + pos] = cmp[s];
        }
      }
      __syncthreads();
    }
  } else if (blk - nBB < (N >> 6)) {
    // Transpose/tanh: disjoint LDS array, disjoint blocks.
    int n0 = (blk - nBB) * 64;
    for (int k = tid; k < 32 * 64; k += 1024) {       // coalesced 256B rows
      int b = k >> 6, n = k & 63;
      tile[b][n] = x[b * N + n0 + n];
    }
    __syncthreads();
    for (int k = tid; k < 64 * 32; k += 1024) {       // coalesced t-layout
      int n = k >> 5, b = k & 31;
      float xv = tile[b][n];
      int j = (n0 + n) * kB + b;
      x_t[j] = xv;
      fx_t[j] = tanhf(xv);
    }
  }
}

// ---- K2/K3: per-bucket fine sort (16 bins, LDS) + per-node VGPR accum. --
// 1024 thr = 32 half-waves = 16 nodes x 2 parts. Records uniform per
// half-wave (LDS broadcast); value gather = 128B coalesced from L2-resident
// 512KB table; accumulator in a single VGPR (no LDS RMW).
__global__ void __launch_bounds__(1024) k_pass(
    const uint2* __restrict__ bucket, const unsigned* __restrict__ gcnt,
    const float* __restrict__ vals, const float* __restrict__ x_t,
    const float* __restrict__ fx_t, float* __restrict__ eps_t,
    float* __restrict__ out, int N, int mode) {
  __shared__ uint2 stg[kCap];            // 20 KB staged records
  __shared__ uint2 srt[kCap];            // 20 KB node-sorted records
  __shared__ unsigned h[kNPB], hb[kNPB], h2[kNPB];
  __shared__ float red[1024];
  int tid = threadIdx.x, t = blockIdx.x;
  int nrec = min((int)gcnt[t], kCap);

  if (tid < kNPB) { h[tid] = 0u; h2[tid] = 0u; }
  __syncthreads();
  for (int i = tid; i < nrec; i += 1024) {            // stage + 16-bin hist
    uint2 r = bucket[(size_t)t * kCap + i];
    stg[i] = r;
    atomicAdd(&h[r.x & 15u], 1u);
  }
  __syncthreads();
  if (tid == 0) {                                     // serial 16-scan
    unsigned run = 0;
#pragma unroll
    for (int l = 0; l < kNPB; l++) { hb[l] = run; run += h[l]; }
  }
  __syncthreads();
  for (int i = tid; i < nrec; i += 1024) {            // LDS fine sort
    uint2 r = stg[i];
    unsigned l = r.x & 15u;
    srt[hb[l] + atomicAdd(&h2[l], 1u)] = r;
  }
  __syncthreads();

  int b = tid & 31, hw = tid >> 5;       // batch lane, half-wave slot
  int l = hw >> 1, part = hw & 1;        // node-in-bucket, edge part
  int beg = (int)hb[l], end = beg + (int)h[l];
  float acc = 0.0f;
  int i = beg + part;
  uint2 z = make_uint2(0u, 0u);
  uint2 r0 = (i < end) ? srt[i] : z;                  // 2-deep value pipeline
  uint2 r1 = (i + 2 < end) ? srt[i + 2] : z;
  float v0 = (i < end) ? vals[((r0.x >> 4) << kLogB) + b] : 0.0f;
  while (i < end) {
    uint2 r2 = (i + 4 < end) ? srt[i + 4] : z;
    float v1 = (i + 2 < end) ? vals[((r1.x >> 4) << kLogB) + b] : 0.0f;
    acc = fmaf(__uint_as_float(r0.y), v0, acc);
    r0 = r1; r1 = r2; v0 = v1;
    i += 2;
  }
  red[tid] = acc;
  __syncthreads();

  if (part == 0) {                       // combine 2 parts, write outputs
    float s = red[tid] + red[tid + 32];
    int n = t * kNPB + l;
    int j = (n << kLogB) + b;
    if (mode == 0) {
      out[b * N + n] = s;                // mu (batch-major; lines merge in L2)
      eps_t[j] = x_t[j] - s;
    } else {
      float fx = fx_t[j];
      out[b * N + n] = fmaf(1.0f - fx * fx, s, -eps_t[j]);   // dx
    }
  }
}

extern "C" void kernel_launch(void* const* d_in, const int* in_sizes, int n_in,
                              void* d_out, int out_size, void* d_ws, size_t ws_size,
                              hipStream_t stream) {
  const float* x    = (const float*)d_in[0];
  const float* w    = (const float*)d_in[1];
  const int*   esrc = (const int*)d_in[2];
  const int*   edst = (const int*)d_in[3];

  int BN = in_sizes[0];                  // 131072
  int E  = in_sizes[1];                  // 524288
  int N  = BN / kB;                      // 4096
  int nBB = (E + kChunk - 1) / kChunk;   // 128

  float* ws    = (float*)d_ws;
  float* x_t   = ws;                     // [BN]
  float* fx_t  = ws + (size_t)BN;        // [BN]
  float* eps_t = ws + 2 * (size_t)BN;    // [BN]
  unsigned* gcntA = (unsigned*)(ws + 3 * (size_t)BN);   // [256]
  unsigned* gcntB = gcntA + kBkt;                       // [256]
  uint2* bucketA = (uint2*)(gcntB + kBkt);              // [256*2560] 5.2 MB
  uint2* bucketB = bucketA + (size_t)kBkt * kCap;       // [256*2560] 5.2 MB

  float* out_mu = (float*)d_out;
  float* out_dx = (float*)d_out + BN;

  // Zero bucket counters (workspace is poisoned each iteration).
  hipMemsetAsync(gcntA, 0, (size_t)2 * kBkt * sizeof(unsigned), stream);

  k_bucket<<<nBB + (N >> 6), 1024, 0, stream>>>(x, w, esrc, edst, x_t, fx_t,
                                                gcntA, gcntB, bucketA, bucketB,
                                                N, E, nBB);
  // Pass 1: mu[n] = sum_{e: dst=n} w_e * fx[src_e]; eps = x - mu.
  k_pass<<<kBkt, 1024, 0, stream>>>(bucketA, gcntA, fx_t, x_t, fx_t,
                                    eps_t, out_mu, N, 0);
  // Pass 2: dx[n] = -eps[n] + f'(x_n) * sum_{e: src=n} w_e * eps[dst_e].
  k_pass<<<kBkt, 1024, 0, stream>>>(bucketB, gcntB, eps_t, x_t, fx_t,
                                    eps_t, out_dx, N, 1);
}